// Round 4
// baseline (163.522 us; speedup 1.0000x reference)
//
#include <hip/hip_runtime.h>
#include <hip/hip_bf16.h>
#include <math.h>

#define N_CLASSES 1000
#define FEAT_DIM 1024
#define PROJ_DIM 256
#define BATCH 32
#define NUM_SUPPORT 8192
#define KBIG 3072   // [Ah | Ah | Al] x [Wh ; Wl ; Wh]
#define ACOLS 2048  // stored A: row = [Ah(1024) | Al(1024)]
#define KSLICES 4
#define KSLICE (KBIG / KSLICES)  // 768, multiple of 64; term boundary at 1024 ok

typedef __attribute__((ext_vector_type(8))) short bf16x8;
typedef __attribute__((ext_vector_type(4))) float f32x4;

__device__ inline unsigned short bf16bits(float v) {
  __hip_bfloat16 h = __float2bfloat16(v);
  return *reinterpret_cast<unsigned short*>(&h);
}
__device__ inline float bf16tof(unsigned short u) {
  __hip_bfloat16 h;
  *reinterpret_cast<unsigned short*>(&h) = u;
  return __bfloat162float(h);
}

// Monotonic float <-> unsigned encoding for atomicMax on floats.
__device__ inline unsigned enc_f(float f) {
  unsigned u = __float_as_uint(f);
  return (u & 0x80000000u) ? ~u : (u | 0x80000000u);
}
__device__ inline float dec_f(unsigned e) {
  return (e & 0x80000000u) ? __uint_as_float(e & 0x7FFFFFFFu)
                           : __uint_as_float(~e);
}

// ---------------------------------------------------------------------------
// prep_A: sx (8192x1024 f32) -> A2 (8192x2048 bf16): row = [hi(1024)|lo(1024)]
// ---------------------------------------------------------------------------
__global__ __launch_bounds__(256) void prep_a_kernel(
    const float* __restrict__ sx, unsigned short* __restrict__ A2) {
  const int idx = blockIdx.x * 256 + threadIdx.x;
  const int r = idx >> 8;
  const int q = idx & 255;
  const float4 v = *(const float4*)&sx[(size_t)r * FEAT_DIM + q * 4];
  const float vv[4] = {v.x, v.y, v.z, v.w};
  ushort4 h, l;
  unsigned short hb[4], lb[4];
#pragma unroll
  for (int i = 0; i < 4; i++) {
    hb[i] = bf16bits(vv[i]);
    lb[i] = bf16bits(vv[i] - bf16tof(hb[i]));
  }
  h.x = hb[0]; h.y = hb[1]; h.z = hb[2]; h.w = hb[3];
  l.x = lb[0]; l.y = lb[1]; l.z = lb[2]; l.w = lb[3];
  *(ushort4*)&A2[(size_t)r * ACOLS + q * 4] = h;
  *(ushort4*)&A2[(size_t)r * ACOLS + 1024 + q * 4] = l;
}

// ---------------------------------------------------------------------------
// prep_W: W (1024x256 f32, k-major) -> WT (256x3072 bf16, n-major):
// WT[n] = [Wh(k 0..1023) | Wl | Wh]
// ---------------------------------------------------------------------------
__global__ __launch_bounds__(256) void prep_w_kernel(
    const float* __restrict__ W, unsigned short* __restrict__ WT) {
  const int idx = blockIdx.x * 256 + threadIdx.x;  // 256*1024
  const int n = idx >> 10;
  const int k = idx & 1023;
  const float v = W[(size_t)k * PROJ_DIM + n];
  const unsigned short h = bf16bits(v);
  const unsigned short l = bf16bits(v - bf16tof(h));
  WT[(size_t)n * KBIG + k] = h;
  WT[(size_t)n * KBIG + 1024 + k] = l;
  WT[(size_t)n * KBIG + 2048 + k] = h;
}

// ---------------------------------------------------------------------------
// proj_x: xq = x @ W (fp32). Grid (32 b, 8 col-chunks), 256 thr = 32c x 8k.
// Also inits rowmaxU.
// ---------------------------------------------------------------------------
__global__ __launch_bounds__(256) void proj_x_kernel(
    const float* __restrict__ x, const float* __restrict__ W,
    float* __restrict__ xq, unsigned* __restrict__ rowmaxU) {
  __shared__ float part[256];
  const int b = blockIdx.x, cc = blockIdx.y;
  const int t = threadIdx.x;
  if (b == 0 && cc == 0 && t < BATCH) rowmaxU[t] = 0u;

  const int col = t & 31, ks = t >> 5;
  const int gc = cc * 32 + col;
  const int k0 = ks * 128;
  float s = 0.f;
#pragma unroll 8
  for (int k = 0; k < 128; k++) {
    s = fmaf(x[(size_t)b * FEAT_DIM + k0 + k],
             W[(size_t)(k0 + k) * PROJ_DIM + gc], s);
  }
  part[t] = s;
  __syncthreads();
  if (t < 32) {
    float acc = 0.f;
#pragma unroll
    for (int i = 0; i < 8; i++) acc += part[i * 32 + t];
    xq[(size_t)b * PROJ_DIM + cc * 32 + t] = acc;
  }
}

// ---------------------------------------------------------------------------
// sxp = A2(split bf16) @ WT^T via MFMA, K=3072 split into 4 slices of 768.
// Tile 128x64, BK=64, 4 waves (2x2), wave tile 64x32 (4x2 frags of 16x16x32).
// Grid (64, 4, 4) = 1024 blocks = 4/CU. Epilogue: fp32 atomicAdd into zeroed
// sxp (split-K combine).
// ---------------------------------------------------------------------------
__global__ __launch_bounds__(256) void sxp_mfma_kernel(
    const unsigned short* __restrict__ A2, const unsigned short* __restrict__ WT,
    float* __restrict__ sxp) {
  __shared__ unsigned short At[128 * 64];  // row r: 8 chunks of 8 shorts
  __shared__ unsigned short Bt[64 * 64];

  const int tid = threadIdx.x;
  const int w = tid >> 6;
  const int lane = tid & 63;
  const int bm = blockIdx.x * 128;
  const int bn = blockIdx.y * 64;
  const int kz = blockIdx.z;
  const int wm = w & 1, wn = w >> 1;
  const int m16 = lane & 15, quad = lane >> 4;
  const int lrow8 = lane >> 3;       // 0..7
  const int g = (lane & 7) ^ lrow8;  // XOR-swizzled global chunk index

  f32x4 acc[4][2];
#pragma unroll
  for (int mt = 0; mt < 4; mt++)
#pragma unroll
    for (int nt = 0; nt < 2; nt++) acc[mt][nt] = (f32x4){0.f, 0.f, 0.f, 0.f};

  const int kb0 = kz * KSLICE;
  for (int kk = 0; kk < KSLICE; kk += 64) {
    const int kb = kb0 + kk;
    const int acol = (kb < 1024) ? kb : kb - 1024;
    // stage A tile (128 x 64 bf16): 4 instrs/wave, 8 rows each
#pragma unroll
    for (int i = 0; i < 4; i++) {
      const int row = w * 32 + i * 8 + lrow8;
      const unsigned short* gp = A2 + (size_t)(bm + row) * ACOLS + acol + g * 8;
      __builtin_amdgcn_global_load_lds(
          (const __attribute__((address_space(1))) void*)gp,
          (__attribute__((address_space(3))) void*)(At + (w * 32 + i * 8) * 64),
          16, 0, 0);
    }
    // stage B tile (64 n x 64 k bf16): 2 instrs/wave
#pragma unroll
    for (int i = 0; i < 2; i++) {
      const int nrow = w * 16 + i * 8 + lrow8;
      const unsigned short* gp = WT + (size_t)(bn + nrow) * KBIG + kb + g * 8;
      __builtin_amdgcn_global_load_lds(
          (const __attribute__((address_space(1))) void*)gp,
          (__attribute__((address_space(3))) void*)(Bt + (w * 16 + i * 8) * 64),
          16, 0, 0);
    }
    __syncthreads();

#pragma unroll
    for (int s = 0; s < 2; s++) {
      const int slot = (s * 4 + quad) ^ (m16 & 7);
      bf16x8 af[4], bf[2];
#pragma unroll
      for (int mt = 0; mt < 4; mt++) {
        const int row = wm * 64 + mt * 16 + m16;
        af[mt] = *(bf16x8*)&At[row * 64 + slot * 8];
      }
#pragma unroll
      for (int nt = 0; nt < 2; nt++) {
        const int nrow = wn * 32 + nt * 16 + m16;
        bf[nt] = *(bf16x8*)&Bt[nrow * 64 + slot * 8];
      }
#pragma unroll
      for (int mt = 0; mt < 4; mt++)
#pragma unroll
        for (int nt = 0; nt < 2; nt++)
          acc[mt][nt] = __builtin_amdgcn_mfma_f32_16x16x32_bf16(
              af[mt], bf[nt], acc[mt][nt], 0, 0, 0);
    }
    __syncthreads();
  }

  // split-K combine: atomicAdd into zeroed sxp.
  // C/D layout: col = lane&15 (n), row = quad*4 + reg (m)
#pragma unroll
  for (int mt = 0; mt < 4; mt++)
#pragma unroll
    for (int nt = 0; nt < 2; nt++)
#pragma unroll
      for (int r = 0; r < 4; r++) {
        const int mg = bm + wm * 64 + mt * 16 + quad * 4 + r;
        const int ng = bn + wn * 32 + nt * 16 + m16;
        atomicAdd(&sxp[(size_t)mg * PROJ_DIM + ng], acc[mt][nt][r]);
      }
}

// ---------------------------------------------------------------------------
// score: scores[b][j] = 2<xq_b, sxp_j> - ||sxp_j||^2 - ||xq_b||^2
// Grid (32 j-chunks, 8 b-groups of 4). x_sq computed in-block.
// ---------------------------------------------------------------------------
__global__ __launch_bounds__(256) void score_kernel(
    const float* __restrict__ xq, const float* __restrict__ sxp,
    float* __restrict__ sc, unsigned* __restrict__ rowmaxU) {
  __shared__ float xqT4[PROJ_DIM * 4];
  __shared__ float xsqL[4];
  __shared__ float redm[4][4];

  const int t = threadIdx.x;
  const int jc = blockIdx.x;
  const int bg = blockIdx.y;
  const int lane = t & 63, wave = t >> 6;

  float xv[4];
#pragma unroll
  for (int i = 0; i < 4; i++) {
    xv[i] = xq[(size_t)(bg * 4 + i) * PROJ_DIM + t];
    xqT4[t * 4 + i] = xv[i];
  }
#pragma unroll
  for (int i = 0; i < 4; i++) {
    float v = xv[i] * xv[i];
#pragma unroll
    for (int o = 1; o < 64; o <<= 1) v += __shfl_xor(v, o, 64);
    if (lane == 0) redm[i][wave] = v;
  }
  __syncthreads();
  if (t < 4) xsqL[t] = redm[t][0] + redm[t][1] + redm[t][2] + redm[t][3];
  __syncthreads();

  const int j = jc * 256 + t;
  const float4* __restrict__ row4 = (const float4*)(sxp + (size_t)j * PROJ_DIM);
  float dot[4] = {0.f, 0.f, 0.f, 0.f};
  float rsq = 0.f;

#pragma unroll 4
  for (int q = 0; q < PROJ_DIM / 4; q++) {
    const float4 rv = row4[q];
    const float rr[4] = {rv.x, rv.y, rv.z, rv.w};
#pragma unroll
    for (int c = 0; c < 4; c++) {
      const int p = q * 4 + c;
      const float4 xb = *(const float4*)&xqT4[p * 4];
      rsq = fmaf(rr[c], rr[c], rsq);
      dot[0] = fmaf(rr[c], xb.x, dot[0]);
      dot[1] = fmaf(rr[c], xb.y, dot[1]);
      dot[2] = fmaf(rr[c], xb.z, dot[2]);
      dot[3] = fmaf(rr[c], xb.w, dot[3]);
    }
  }

#pragma unroll
  for (int c = 0; c < 4; c++) {
    const float s = 2.0f * dot[c] - rsq - xsqL[c];
    sc[(size_t)(bg * 4 + c) * NUM_SUPPORT + j] = s;
    float v = s;
#pragma unroll
    for (int o = 1; o < 64; o <<= 1) v = fmaxf(v, __shfl_xor(v, o, 64));
    if (lane == 0) redm[c][wave] = v;
  }
  __syncthreads();
  if (t < 4) {
    const float m =
        fmaxf(fmaxf(redm[t][0], redm[t][1]), fmaxf(redm[t][2], redm[t][3]));
    atomicMax(&rowmaxU[bg * 4 + t], enc_f(m));
  }
}

// ---------------------------------------------------------------------------
// finish: exp, class bins, log. One block (1024 thr) per batch row.
// ---------------------------------------------------------------------------
__global__ __launch_bounds__(1024) void finish_kernel(
    const float* __restrict__ sc, const unsigned* __restrict__ rowmaxU,
    const int* __restrict__ sy, float* __restrict__ out) {
  __shared__ float cls[N_CLASSES];
  __shared__ float red[16];

  const int b = blockIdx.x;
  const int t = threadIdx.x;
  const int lane = t & 63, wave = t >> 6;
  const float m = dec_f(rowmaxU[b]);

  for (int c = t; c < N_CLASSES; c += 1024) cls[c] = 0.0f;
  __syncthreads();

  float lsum = 0.0f;
#pragma unroll
  for (int jj = 0; jj < NUM_SUPPORT / 1024; jj++) {
    const int j = jj * 1024 + t;
    const float e = expf(sc[(size_t)b * NUM_SUPPORT + j] - m);
    lsum += e;
    atomicAdd(&cls[sy[j]], e);
  }
#pragma unroll
  for (int o = 1; o < 64; o <<= 1) lsum += __shfl_xor(lsum, o, 64);
  if (lane == 0) red[wave] = lsum;
  __syncthreads();
  if (t == 0) {
    float s = 0.f;
#pragma unroll
    for (int i = 0; i < 16; i++) s += red[i];
    red[0] = s;
  }
  __syncthreads();
  const float inv = 1.0f / red[0];
  for (int c = t; c < N_CLASSES; c += 1024) {
    out[(size_t)b * N_CLASSES + c] = logf(cls[c] * inv + 1e-12f);
  }
}

// ---------------------------------------------------------------------------
extern "C" void kernel_launch(void* const* d_in, const int* in_sizes, int n_in,
                              void* d_out, int out_size, void* d_ws,
                              size_t ws_size, hipStream_t stream) {
  const float* x = (const float*)d_in[0];   // (32, 1024)
  const float* sx = (const float*)d_in[1];  // (8192, 1024)
  const float* W = (const float*)d_in[2];   // (1024, 256)
  const int* sy = (const int*)d_in[3];      // (8192,)
  float* out = (float*)d_out;               // (32, 1000)

  char* p = (char*)d_ws;
  float* xq = (float*)p;            p += (size_t)BATCH * PROJ_DIM * 4;
  unsigned* rowmaxU = (unsigned*)p; p += 128;
  float* sxp = (float*)p;           p += (size_t)NUM_SUPPORT * PROJ_DIM * 4;
  float* sc = (float*)p;            p += (size_t)BATCH * NUM_SUPPORT * 4;
  unsigned short* A2 = (unsigned short*)p; p += (size_t)NUM_SUPPORT * ACOLS * 2;
  unsigned short* WT = (unsigned short*)p;  // 256*3072*2

  prep_w_kernel<<<dim3(1024), dim3(256), 0, stream>>>(W, WT);
  prep_a_kernel<<<dim3(NUM_SUPPORT), dim3(256), 0, stream>>>(sx, A2);
  proj_x_kernel<<<dim3(BATCH, 8), dim3(256), 0, stream>>>(x, W, xq, rowmaxU);
  // zero sxp for split-K atomic accumulation
  hipMemsetAsync(sxp, 0, (size_t)NUM_SUPPORT * PROJ_DIM * 4, stream);
  sxp_mfma_kernel<<<dim3(NUM_SUPPORT / 128, PROJ_DIM / 64, KSLICES), dim3(256),
                    0, stream>>>(A2, WT, sxp);
  score_kernel<<<dim3(NUM_SUPPORT / 256, BATCH / 4), dim3(256), 0, stream>>>(
      xq, sxp, sc, rowmaxU);
  finish_kernel<<<dim3(BATCH), dim3(1024), 0, stream>>>(sc, rowmaxU, sy, out);
}